// Round 5
// baseline (120.157 us; speedup 1.0000x reference)
//
#include <hip/hip_runtime.h>
#include <hip/hip_bf16.h>

// DecorrelationGradient, KAPPA = 0.5:
//   out = 0.5 * (X^T X / N) - 0.5   (diag terms cancel exactly at k=0.5)
// X [16384, 768] fp32.
//
// R5: gemm was latency/barrier-bound (~25us, 2.6 blocks/CU, 16 vmcnt(0)
//     barriers). -> 512-thr blocks (5.25 waves/SIMD), BK=64 double-stage
//     (8 barrier pairs), f32 partials (coalesced 64B epilogue segments),
//     mirror fused into reduce (one fewer launch).
// K1: transpose+cast X -> XT [768,16384] bf16
// K2: MFMA GEMM, upper tile-pairs, 128x128, BK=64(2x32), KSPLIT=32, f32 partials
// K3: reduce 32 partials -> affine -> write upper tile + mirrored transpose

#define D_DIM    768
#define K_DIM    16384
#define NPAIR    21
#define KSPLIT   32
#define XT_BYTES   ((size_t)D_DIM * K_DIM * 2)                // 24 MiB
#define PART_BYTES ((size_t)KSPLIT * NPAIR * 16384 * 4)       // 42 MiB f32

__device__ __constant__ int MI_TAB[NPAIR] = {0,0,0,0,0,0, 1,1,1,1,1, 2,2,2,2, 3,3,3, 4,4, 5};
__device__ __constant__ int NI_TAB[NPAIR] = {0,1,2,3,4,5, 1,2,3,4,5, 2,3,4,5, 3,4,5, 4,5, 5};

typedef __attribute__((ext_vector_type(8))) short short8;     // bf16 A/B frag
typedef __attribute__((ext_vector_type(4))) float floatx4;    // fp32 C/D frag

typedef __attribute__((address_space(3))) unsigned short lds_ushort;
typedef __attribute__((address_space(1))) const unsigned short g_ushort;

__device__ __forceinline__ void load_lds16(const unsigned short* g, unsigned short* l) {
  __builtin_amdgcn_global_load_lds((g_ushort*)g, (lds_ushort*)l, 16, 0, 0);
}

__device__ __forceinline__ unsigned int f2bf_u(float f) {     // RNE, as uint
  unsigned int u = __float_as_uint(f);
  u += 0x7fffu + ((u >> 16) & 1u);
  return u >> 16;
}

// ---------------- K1: transpose + cast (R4 version, ~floor-ish) ------------
__global__ __launch_bounds__(256) void transpose_cast_kernel(
    const float* __restrict__ x, unsigned short* __restrict__ xt) {
  __shared__ __align__(16) unsigned int tileT[64 * 33];   // [d][npair]
  const int d0 = blockIdx.x * 64;
  const int n0 = blockIdx.y * 64;
  const int t  = threadIdx.x;
  const int f4 = t & 15;
  const int np = t >> 4;
#pragma unroll
  for (int j = 0; j < 2; ++j) {
    const int npg = np + 16 * j;
    const float* p0 = x + (size_t)(n0 + 2 * npg) * D_DIM + d0 + 4 * f4;
    float4 v0 = *(const float4*)p0;
    float4 v1 = *(const float4*)(p0 + D_DIM);
    tileT[(4 * f4 + 0) * 33 + npg] = f2bf_u(v0.x) | (f2bf_u(v1.x) << 16);
    tileT[(4 * f4 + 1) * 33 + npg] = f2bf_u(v0.y) | (f2bf_u(v1.y) << 16);
    tileT[(4 * f4 + 2) * 33 + npg] = f2bf_u(v0.z) | (f2bf_u(v1.z) << 16);
    tileT[(4 * f4 + 3) * 33 + npg] = f2bf_u(v0.w) | (f2bf_u(v1.w) << 16);
  }
  __syncthreads();
  const int ch = t & 7;
  const int dr = t >> 3;
#pragma unroll
  for (int j = 0; j < 2; ++j) {
    const int dd = dr + 32 * j;
    const unsigned int* row = &tileT[dd * 33 + ch * 4];
    uint4 o; o.x = row[0]; o.y = row[1]; o.z = row[2]; o.w = row[3];
    *(uint4*)(xt + (size_t)(d0 + dd) * K_DIM + n0 + ch * 8) = o;
  }
}

// ---------------- K2: Gram GEMM, 512 threads, BK=64 double-stage -----------
// grid (NPAIR, KSPLIT). 8 waves: wave-tile 32x64 at (wm = (w&3)*32, wn = (w>>2)*64).
__global__ __launch_bounds__(512, 4) void gram_gemm_kernel(
    const unsigned short* __restrict__ xt,
    float* __restrict__ partials) {          // f32 [KSPLIT][NPAIR][16384]
  __shared__ __align__(16) unsigned short ldsA[2][128 * 32];  // [half][row*32+k]
  __shared__ __align__(16) unsigned short ldsB[2][128 * 32];

  const int p  = blockIdx.x;
  const int mi = MI_TAB[p];
  const int ni = NI_TAB[p];
  const int m0 = mi * 128;
  const int n0 = ni * 128;
  const int kz = blockIdx.y;

  const int t    = threadIdx.x;
  const int wave = t >> 6;
  const int lane = t & 63;
  const int wm   = (wave & 3) * 32;
  const int wn   = (wave >> 2) * 64;
  const int lm   = lane & 15;
  const int quad = lane >> 4;

  floatx4 zero = {0.f, 0.f, 0.f, 0.f};
  floatx4 acc[2][4];
#pragma unroll
  for (int a = 0; a < 2; ++a)
#pragma unroll
    for (int b = 0; b < 4; ++b) acc[a][b] = zero;

  const int kbeg = kz * (K_DIM / KSPLIT);
  // staging: each half-slab = 128 rows x 32 bf16 (64 B/row) = 512 lane-loads
  // = exactly 1 global_load_lds per thread. lanes t&3 cover one row's 64 B.
  const int rrow = t >> 2;
  const int sub  = t & 3;

  for (int it = 0; it < (K_DIM / KSPLIT) / 64; ++it) {   // 8 iters of BK=64
    const int kb = kbeg + it * 64;
#pragma unroll
    for (int h = 0; h < 2; ++h) {
      const unsigned short* gA = xt + (size_t)(m0 + rrow) * K_DIM + kb + h * 32 + sub * 8;
      const unsigned short* gB = xt + (size_t)(n0 + rrow) * K_DIM + kb + h * 32 + sub * 8;
      load_lds16(gA, &ldsA[h][t * 8]);
      load_lds16(gB, &ldsB[h][t * 8]);
    }
    __syncthreads();

#pragma unroll
    for (int h = 0; h < 2; ++h) {
      short8 af[2], bf[4];
#pragma unroll
      for (int a = 0; a < 2; ++a)
        af[a] = *(const short8*)&ldsA[h][(wm + a * 16 + lm) * 32 + quad * 8];
#pragma unroll
      for (int b = 0; b < 4; ++b)
        bf[b] = *(const short8*)&ldsB[h][(wn + b * 16 + lm) * 32 + quad * 8];
#pragma unroll
      for (int a = 0; a < 2; ++a)
#pragma unroll
        for (int b = 0; b < 4; ++b)
          acc[a][b] = __builtin_amdgcn_mfma_f32_16x16x32_bf16(
              af[a], bf[b], acc[a][b], 0, 0, 0);
    }
    __syncthreads();
  }

  // epilogue: f32 partial, local 128x128 row-major; lanes(lm) give 64 B segments
  float* pb = partials + ((size_t)kz * NPAIR + p) * 16384;
#pragma unroll
  for (int a = 0; a < 2; ++a)
#pragma unroll
    for (int b = 0; b < 4; ++b)
#pragma unroll
      for (int r2 = 0; r2 < 4; ++r2) {
        const int lr = wm + a * 16 + quad * 4 + r2;
        const int lc = wn + b * 16 + lm;
        pb[lr * 128 + lc] = acc[a][b][r2];
      }
}

// ---------------- K3: reduce + affine + fused mirror -----------------------
// grid: 21 tiles x 8 segs = 168 blocks. Block covers 16 rows x 128 cols.
__global__ __launch_bounds__(256) void reduce_kernel(
    const float* __restrict__ partials, float* __restrict__ out) {
  __shared__ float lt[16 * 129];
  const int blk = blockIdx.x;
  const int p   = blk >> 3;
  const int seg = blk & 7;
  const int tid = threadIdx.x;
  const int e0  = seg * 2048 + tid * 8;       // elem base in 128x128 tile
  float s[8];
#pragma unroll
  for (int i = 0; i < 8; ++i) s[i] = 0.f;
#pragma unroll
  for (int kz = 0; kz < KSPLIT; ++kz) {
    const float* pp = partials + ((size_t)kz * NPAIR + p) * 16384 + e0;
    const float4 v0 = *(const float4*)pp;
    const float4 v1 = *(const float4*)(pp + 4);
    s[0] += v0.x; s[1] += v0.y; s[2] += v0.z; s[3] += v0.w;
    s[4] += v1.x; s[5] += v1.y; s[6] += v1.z; s[7] += v1.w;
  }
  const float scale = 0.5f / (float)K_DIM;
  float v[8];
#pragma unroll
  for (int i = 0; i < 8; ++i) v[i] = fmaf(s[i], scale, -0.5f);

  const int mi = MI_TAB[p], ni = NI_TAB[p];
  const int r = e0 >> 7;                      // row within tile (seg*16 + tid/16)
  const int c = e0 & 127;                     // col base
  float* o = out + (size_t)(mi * 128 + r) * D_DIM + ni * 128 + c;
  *(float4*)o       = make_float4(v[0], v[1], v[2], v[3]);
  *(float4*)(o + 4) = make_float4(v[4], v[5], v[6], v[7]);

  if (mi != ni) {
    // stage block's 16x128 into LDS, write transposed 128x16 to lower tile
    const int lr = r - seg * 16;              // 0..15
#pragma unroll
    for (int i = 0; i < 8; ++i) lt[lr * 129 + c + i] = v[i];
    __syncthreads();
    const int ct   = tid & 127;               // source col -> dest row
    const int half = tid >> 7;                // 0/1 -> dest col group of 8
    float w[8];
#pragma unroll
    for (int i = 0; i < 8; ++i) w[i] = lt[(half * 8 + i) * 129 + ct];
    float* od = out + (size_t)(ni * 128 + ct) * D_DIM + mi * 128 + seg * 16 + half * 8;
    *(float4*)od       = make_float4(w[0], w[1], w[2], w[3]);
    *(float4*)(od + 4) = make_float4(w[4], w[5], w[6], w[7]);
  }
}

// ---------------- fallback (small ws): atomic path -------------------------
__global__ __launch_bounds__(256) void init_out_kernel(float* __restrict__ out) {
  size_t i = (size_t)blockIdx.x * 256 + threadIdx.x;
  ((float4*)out)[i] = make_float4(-0.5f, -0.5f, -0.5f, -0.5f);
}
__global__ __launch_bounds__(256, 4) void gram_gemm_atomic_kernel(
    const unsigned short* __restrict__ xt, float* __restrict__ out) {
  __shared__ __align__(16) unsigned short ldsA[128 * 32];
  __shared__ __align__(16) unsigned short ldsB[128 * 32];
  const int p  = blockIdx.x;
  const int mi = MI_TAB[p];
  const int ni = NI_TAB[p];
  const int m0 = mi * 128, n0 = ni * 128;
  const int kz = blockIdx.y;
  const int t = threadIdx.x, wave = t >> 6, lane = t & 63;
  const int wm = (wave >> 1) * 64, wn = (wave & 1) * 64;
  const int lm = lane & 15, quad = lane >> 4;
  floatx4 zero = {0.f, 0.f, 0.f, 0.f};
  floatx4 acc[4][4];
#pragma unroll
  for (int a = 0; a < 4; ++a)
#pragma unroll
    for (int b = 0; b < 4; ++b) acc[a][b] = zero;
  const int kbeg = kz * (K_DIM / 8);
  for (int it = 0; it < (K_DIM / 8) / 32; ++it) {
    const int kb = kbeg + it * 32;
#pragma unroll
    for (int i = 0; i < 2; ++i) {
      const int flatL = (wave * 2 + i) * 64 + lane;
      const int rr = flatL >> 2, sb = flatL & 3;
      load_lds16(xt + (size_t)(m0 + rr) * K_DIM + kb + sb * 8, &ldsA[flatL * 8]);
      load_lds16(xt + (size_t)(n0 + rr) * K_DIM + kb + sb * 8, &ldsB[flatL * 8]);
    }
    __syncthreads();
    short8 af[4], bf[4];
#pragma unroll
    for (int a = 0; a < 4; ++a)
      af[a] = *(const short8*)&ldsA[(wm + a * 16 + lm) * 32 + quad * 8];
#pragma unroll
    for (int b = 0; b < 4; ++b)
      bf[b] = *(const short8*)&ldsB[(wn + b * 16 + lm) * 32 + quad * 8];
#pragma unroll
    for (int a = 0; a < 4; ++a)
#pragma unroll
      for (int b = 0; b < 4; ++b)
        acc[a][b] = __builtin_amdgcn_mfma_f32_16x16x32_bf16(af[a], bf[b], acc[a][b], 0, 0, 0);
    __syncthreads();
  }
  const float scale = 0.5f / (float)K_DIM;
#pragma unroll
  for (int a = 0; a < 4; ++a)
#pragma unroll
    for (int b = 0; b < 4; ++b)
#pragma unroll
      for (int r2 = 0; r2 < 4; ++r2) {
        const int gr = m0 + wm + a * 16 + quad * 4 + r2;
        const int gc = n0 + wn + b * 16 + lm;
        atomicAdd(&out[(size_t)gr * D_DIM + gc], acc[a][b][r2] * scale);
        if (mi != ni)
          atomicAdd(&out[(size_t)gc * D_DIM + gr], acc[a][b][r2] * scale);
      }
}

extern "C" void kernel_launch(void* const* d_in, const int* in_sizes, int n_in,
                              void* d_out, int out_size, void* d_ws, size_t ws_size,
                              hipStream_t stream) {
  const float* x = (const float*)d_in[0];           // [16384,768] f32
  float* out = (float*)d_out;                       // [768,768] f32
  unsigned short* xt = (unsigned short*)d_ws;       // bf16 [768][16384]

  transpose_cast_kernel<<<dim3(12, 256), 256, 0, stream>>>(x, xt);

  if (ws_size >= XT_BYTES + PART_BYTES) {
    float* parts = (float*)((char*)d_ws + XT_BYTES);
    gram_gemm_kernel<<<dim3(NPAIR, KSPLIT), 512, 0, stream>>>(xt, parts);
    reduce_kernel<<<NPAIR * 8, 256, 0, stream>>>(parts, out);
  } else {
    init_out_kernel<<<576, 256, 0, stream>>>(out);
    gram_gemm_atomic_kernel<<<dim3(NPAIR, 8), 256, 0, stream>>>(xt, out);
  }
}